// Round 1
// 2221.892 us; speedup vs baseline: 2.1347x; 2.1347x over previous
//
#include <hip/hip_runtime.h>
#include <math.h>

#define B_ 4
#define S_ 2048
#define H_ 16
#define DK 64
#define DM 1024  // H_*DK

typedef __attribute__((ext_vector_type(4))) float f4;
typedef __attribute__((ext_vector_type(8))) short sh8;   // 8 bf16 (4 VGPRs) — MFMA A/B frag
typedef __attribute__((ext_vector_type(4))) short sh4;

__device__ __forceinline__ short f2bf(float x) {
  // round-to-nearest-even fp32 -> bf16 (values here are bounded normals)
  unsigned u = __builtin_bit_cast(unsigned, x);
  u += 0x7FFFu + ((u >> 16) & 1u);
  return (short)(u >> 16);
}

#define MFMA(a, b, c) __builtin_amdgcn_mfma_f32_16x16x32_bf16((a), (b), (c), 0, 0, 0)

// ---------------------------------------------------------------------------
// Tiled fp32 GEMM: C = A[M,K] @ W[K,N] + bias[N]   (unchanged this round)
// ---------------------------------------------------------------------------
template <int OUT_LAYOUT>
__global__ __launch_bounds__(256) void gemm128(const float* __restrict__ A,
                                               const float* __restrict__ W,
                                               const float* __restrict__ bias,
                                               float* __restrict__ C) {
  const int K = 1024, N = 1024;
  __shared__ float As[16 * 136];  // [k][m], padded stride 136
  __shared__ float Bs[16 * 136];  // [k][n]
  const int t = threadIdx.x;
  const int tn = t & 15, tm = t >> 4;
  const int bm = blockIdx.y * 128, bn = blockIdx.x * 128;

  float acc[8][8];
#pragma unroll
  for (int i = 0; i < 8; ++i)
#pragma unroll
    for (int j = 0; j < 8; ++j) acc[i][j] = 0.f;

  for (int k0 = 0; k0 < K; k0 += 16) {
    __syncthreads();
#pragma unroll
    for (int u = 0; u < 2; ++u) {
      int f = t + u * 256;
      int ar = f >> 2, ac4 = (f & 3) * 4;
      float4 av = *(const float4*)&A[(size_t)(bm + ar) * K + k0 + ac4];
      As[(ac4 + 0) * 136 + ar] = av.x;
      As[(ac4 + 1) * 136 + ar] = av.y;
      As[(ac4 + 2) * 136 + ar] = av.z;
      As[(ac4 + 3) * 136 + ar] = av.w;
      int br = f >> 5, bc4 = (f & 31) * 4;
      float4 bv = *(const float4*)&W[(size_t)(k0 + br) * N + bn + bc4];
      *(float4*)&Bs[br * 136 + bc4] = bv;
    }
    __syncthreads();
#pragma unroll
    for (int k = 0; k < 16; ++k) {
      float a[8], b[8];
      *(float4*)&a[0] = *(const float4*)&As[k * 136 + tm * 8];
      *(float4*)&a[4] = *(const float4*)&As[k * 136 + tm * 8 + 4];
      *(float4*)&b[0] = *(const float4*)&Bs[k * 136 + tn * 8];
      *(float4*)&b[4] = *(const float4*)&Bs[k * 136 + tn * 8 + 4];
#pragma unroll
      for (int i = 0; i < 8; ++i)
#pragma unroll
        for (int j = 0; j < 8; ++j) acc[i][j] += a[i] * b[j];
    }
  }

  float bb[8];
  *(float4*)&bb[0] = *(const float4*)&bias[bn + tn * 8];
  *(float4*)&bb[4] = *(const float4*)&bias[bn + tn * 8 + 4];
#pragma unroll
  for (int i = 0; i < 8; ++i) {
    int m = bm + tm * 8 + i;
#pragma unroll
    for (int j4 = 0; j4 < 8; j4 += 4) {
      float4 vv = make_float4(acc[i][j4 + 0] + bb[j4 + 0], acc[i][j4 + 1] + bb[j4 + 1],
                              acc[i][j4 + 2] + bb[j4 + 2], acc[i][j4 + 3] + bb[j4 + 3]);
      int n = bn + tn * 8 + j4;
      size_t addr;
      if (OUT_LAYOUT == 0) {
        int b = m >> 11, s = m & 2047;
        int h = n >> 6, dd = n & 63;
        addr = ((size_t)(b * H_ + h) * S_ + s) * DK + dd;
      } else {
        addr = (size_t)m * N + n;
      }
      *(float4*)&C[addr] = vv;
    }
  }
}

// ---------------------------------------------------------------------------
// MFMA attention, 2-pass normalization (no rescale kernel):
//  Block = (qt, b*16+h), 256 thr = 4 waves; wave w owns 16 q-rows.
//  Pass A (kt=0..31): stage K,V->LDS bf16; QK^T via mfma_16x16x32_bf16 (fp32
//    acc); p=exp(s); p->wave-private LDS (bf16); rowsum via mfma(p, ones)
//    (lands broadcast in exactly the lanes that own those rows); PV mfma.
//  Pass B: restage K; recompute QK^T (bit-identical frags); write normalized
//    attn = exp(s)*inv once. Epilogue: ctx = cacc*inv.
//  All A/B frags are 16B ds_read_b128 from stride-72(bf16) rows: conflict-free
//  per 16-lane phase. A/B share the same k-enumeration so the HW fragment
//  k-map cancels (only the verified C/D layout is relied upon).
// ---------------------------------------------------------------------------
__global__ __launch_bounds__(256) void attn_mfma(
    const float* __restrict__ q, const float* __restrict__ kk, const float* __restrict__ vv,
    float* __restrict__ attn, float* __restrict__ ctx) {
  __shared__ __align__(16) short ks[64 * 72];    // [key][d]
  __shared__ __align__(16) short vsT[64 * 72];   // [dv][key]  (transposed at staging)
  __shared__ __align__(16) short ps[4][16 * 72]; // per-wave [qrow_local][key], bf16

  const int t = threadIdx.x;
  const int lane = t & 63;
  const int w = t >> 6;        // wave 0..3
  const int c = lane & 15;     // A-frag row / B-frag col / D col
  const int g = lane >> 4;     // k-group 0..3
  const int qt = blockIdx.x;   // 0..31
  const int bh = blockIdx.y;   // b*16+h
  const int b = bh >> 4, h = bh & 15;
  const size_t qkv_base = (size_t)bh * S_ * DK;
  const size_t attn_base = (size_t)(h * B_ + b) * S_ * (size_t)S_;

  // staging thread mappings
  const int kr = t >> 2, kc16 = (t & 3) << 4;          // K tile: row 0..63, 16-col chunk
  const int vk4 = (t & 15) << 2, vd4 = (t >> 4) << 2;  // V tile: 4 keys x 4 dv patch

  short* psw = &ps[w][0];

  // ---- Q fragments held in registers for the whole kernel (scale folded) ----
  const int qrow_g = qt * 64 + w * 16 + c;  // seq row within (b,h) for A-frags
  sh8 qa[2];
  {
    const float* qp0 = &q[qkv_base + (size_t)qrow_g * DK + g * 8];
#pragma unroll
    for (int s = 0; s < 2; ++s) {
      f4 f0 = *(const f4*)&qp0[s * 32];
      f4 f1 = *(const f4*)&qp0[s * 32 + 4];
      sh8 a;
      a[0] = f2bf(f0[0] * 0.125f); a[1] = f2bf(f0[1] * 0.125f);
      a[2] = f2bf(f0[2] * 0.125f); a[3] = f2bf(f0[3] * 0.125f);
      a[4] = f2bf(f1[0] * 0.125f); a[5] = f2bf(f1[1] * 0.125f);
      a[6] = f2bf(f1[2] * 0.125f); a[7] = f2bf(f1[3] * 0.125f);
      qa[s] = a;
    }
  }

  sh8 ones;
#pragma unroll
  for (int j = 0; j < 8; ++j) ones[j] = (short)0x3F80;  // bf16 1.0

  f4 lsum = {0.f, 0.f, 0.f, 0.f};
  f4 cacc[4];
#pragma unroll
  for (int i = 0; i < 4; ++i) cacc[i] = (f4){0.f, 0.f, 0.f, 0.f};

  // ============================ PASS A ============================
  for (int kt = 0; kt < 32; ++kt) {
    // issue global loads before the barrier (overlap prev compute)
    const float* kbase = &kk[qkv_base + (size_t)(kt * 64 + kr) * DK + kc16];
    f4 kf0 = *(const f4*)&kbase[0];
    f4 kf1 = *(const f4*)&kbase[4];
    f4 kf2 = *(const f4*)&kbase[8];
    f4 kf3 = *(const f4*)&kbase[12];
    const float* vbase = &vv[qkv_base + (size_t)(kt * 64 + vk4) * DK + vd4];
    f4 vf0 = *(const f4*)&vbase[0];
    f4 vf1 = *(const f4*)&vbase[DK];
    f4 vf2 = *(const f4*)&vbase[2 * DK];
    f4 vf3 = *(const f4*)&vbase[3 * DK];

    __syncthreads();  // prev iteration's readers done
    {
      sh8 a0, a1;
      a0[0] = f2bf(kf0[0]); a0[1] = f2bf(kf0[1]); a0[2] = f2bf(kf0[2]); a0[3] = f2bf(kf0[3]);
      a0[4] = f2bf(kf1[0]); a0[5] = f2bf(kf1[1]); a0[6] = f2bf(kf1[2]); a0[7] = f2bf(kf1[3]);
      a1[0] = f2bf(kf2[0]); a1[1] = f2bf(kf2[1]); a1[2] = f2bf(kf2[2]); a1[3] = f2bf(kf2[3]);
      a1[4] = f2bf(kf3[0]); a1[5] = f2bf(kf3[1]); a1[6] = f2bf(kf3[2]); a1[7] = f2bf(kf3[3]);
      *(sh8*)&ks[kr * 72 + kc16] = a0;
      *(sh8*)&ks[kr * 72 + kc16 + 8] = a1;
#pragma unroll
      for (int j = 0; j < 4; ++j) {
        sh4 vw;
        vw[0] = f2bf(vf0[j]); vw[1] = f2bf(vf1[j]);
        vw[2] = f2bf(vf2[j]); vw[3] = f2bf(vf3[j]);
        *(sh4*)&vsT[(vd4 + j) * 72 + vk4] = vw;
      }
    }
    __syncthreads();

    // QK^T + exp + p -> wave-private LDS
#pragma unroll
    for (int kn = 0; kn < 4; ++kn) {
      const sh8 kb0 = *(const sh8*)&ks[(kn * 16 + c) * 72 + g * 8];
      const sh8 kb1 = *(const sh8*)&ks[(kn * 16 + c) * 72 + 32 + g * 8];
      f4 sacc = {0.f, 0.f, 0.f, 0.f};
      sacc = MFMA(qa[0], kb0, sacc);
      sacc = MFMA(qa[1], kb1, sacc);
      // D layout: row = g*4+r (local), col = c
#pragma unroll
      for (int r = 0; r < 4; ++r) {
        float p = __expf(sacc[r]);
        psw[(g * 4 + r) * 72 + kn * 16 + c] = f2bf(p);
      }
    }
    // same-wave DS ops execute in order: no barrier needed (wave-private tile)
    const sh8 pa0 = *(const sh8*)&psw[c * 72 + g * 8];        // keys 0..31
    const sh8 pa1 = *(const sh8*)&psw[c * 72 + 32 + g * 8];   // keys 32..63
    lsum = MFMA(pa0, ones, lsum);  // rowsum, broadcast across cols
    lsum = MFMA(pa1, ones, lsum);
#pragma unroll
    for (int vn = 0; vn < 4; ++vn) {
      const sh8 vb0 = *(const sh8*)&vsT[(vn * 16 + c) * 72 + g * 8];
      const sh8 vb1 = *(const sh8*)&vsT[(vn * 16 + c) * 72 + 32 + g * 8];
      cacc[vn] = MFMA(pa0, vb0, cacc[vn]);
      cacc[vn] = MFMA(pa1, vb1, cacc[vn]);
    }
  }

  // inv lives in exactly the lanes/regs that own rows g*4+r
  f4 inv;
#pragma unroll
  for (int r = 0; r < 4; ++r) inv[r] = 1.0f / lsum[r];

  // ============================ PASS B ============================
  for (int kt = 0; kt < 32; ++kt) {
    const float* kbase = &kk[qkv_base + (size_t)(kt * 64 + kr) * DK + kc16];
    f4 kf0 = *(const f4*)&kbase[0];
    f4 kf1 = *(const f4*)&kbase[4];
    f4 kf2 = *(const f4*)&kbase[8];
    f4 kf3 = *(const f4*)&kbase[12];
    __syncthreads();
    {
      sh8 a0, a1;
      a0[0] = f2bf(kf0[0]); a0[1] = f2bf(kf0[1]); a0[2] = f2bf(kf0[2]); a0[3] = f2bf(kf0[3]);
      a0[4] = f2bf(kf1[0]); a0[5] = f2bf(kf1[1]); a0[6] = f2bf(kf1[2]); a0[7] = f2bf(kf1[3]);
      a1[0] = f2bf(kf2[0]); a1[1] = f2bf(kf2[1]); a1[2] = f2bf(kf2[2]); a1[3] = f2bf(kf2[3]);
      a1[4] = f2bf(kf3[0]); a1[5] = f2bf(kf3[1]); a1[6] = f2bf(kf3[2]); a1[7] = f2bf(kf3[3]);
      *(sh8*)&ks[kr * 72 + kc16] = a0;
      *(sh8*)&ks[kr * 72 + kc16 + 8] = a1;
    }
    __syncthreads();

#pragma unroll
    for (int kn = 0; kn < 4; ++kn) {
      const sh8 kb0 = *(const sh8*)&ks[(kn * 16 + c) * 72 + g * 8];
      const sh8 kb1 = *(const sh8*)&ks[(kn * 16 + c) * 72 + 32 + g * 8];
      f4 sacc = {0.f, 0.f, 0.f, 0.f};
      sacc = MFMA(qa[0], kb0, sacc);
      sacc = MFMA(qa[1], kb1, sacc);
      float* arow = attn + attn_base + (size_t)(qt * 64 + w * 16 + g * 4) * S_ +
                    kt * 64 + kn * 16 + c;
#pragma unroll
      for (int r = 0; r < 4; ++r) {
        arow[(size_t)r * S_] = __expf(sacc[r]) * inv[r];
      }
    }
  }

  // ---- ctx epilogue: [B, S, H*64], normalized ----
#pragma unroll
  for (int vn = 0; vn < 4; ++vn) {
#pragma unroll
    for (int r = 0; r < 4; ++r) {
      size_t a = ((size_t)b * S_ + (qt * 64 + w * 16 + g * 4 + r)) * DM + h * 64 + vn * 16 + c;
      ctx[a] = cacc[vn][r] * inv[r];
    }
  }
}

// ---------------------------------------------------------------------------
extern "C" void kernel_launch(void* const* d_in, const int* in_sizes, int n_in,
                              void* d_out, int out_size, void* d_ws, size_t ws_size,
                              hipStream_t stream) {
  const float* Q  = (const float*)d_in[0];
  const float* K  = (const float*)d_in[1];
  const float* V  = (const float*)d_in[2];
  const float* Wq = (const float*)d_in[3];
  const float* bq = (const float*)d_in[4];
  const float* Wk = (const float*)d_in[5];
  const float* bk = (const float*)d_in[6];
  const float* Wv = (const float*)d_in[7];
  const float* bv = (const float*)d_in[8];
  const float* Wo = (const float*)d_in[9];
  const float* bo = (const float*)d_in[10];

  float* out  = (float*)d_out;
  float* attn = out + (size_t)B_ * S_ * DM;

  float* ws   = (float*)d_ws;
  const size_t PROJ = (size_t)B_ * S_ * DM;  // 8,388,608 floats
  float* qp   = ws;
  float* kp   = qp + PROJ;
  float* vp   = kp + PROJ;
  float* ctx  = vp + PROJ;  // total ws = 128 MB

  dim3 bt(256);
  dim3 gg(8, 64);
  gemm128<0><<<gg, bt, 0, stream>>>(Q, Wq, bq, qp);
  gemm128<0><<<gg, bt, 0, stream>>>(K, Wk, bk, kp);
  gemm128<0><<<gg, bt, 0, stream>>>(V, Wv, bv, vp);
  attn_mfma<<<dim3(32, 64), bt, 0, stream>>>(qp, kp, vp, attn, ctx);
  gemm128<1><<<gg, bt, 0, stream>>>(ctx, Wo, bo, out);
}